// Round 13
// baseline (107.815 us; speedup 1.0000x reference)
//
#include <hip/hip_runtime.h>
#include <hip/hip_bf16.h>
#include <math.h>

#define BN 32
#define NN 2048
#define KK 32
#define DD 16
#define PART_C 16          // per-b partial copies (= n-chunks per b)
#define PART_STRIDE 1056   // per (b,c): [33][32] = (1+16+16) x 32
#define SCAPS 256          // s copies: one per caps chunk -> plain stores

// ws layout (floats):
// 0        : partialA [32*16*1056 = 540672]
// 540672   : partialB [540672]
// 1081344  : s        [256*16384 = 4194304]
// 5275648  : R        [BN*NN*KK = 2097152]
// 7372800  : xpk      [1048576 ushorts = 524288 floats]

typedef __attribute__((ext_vector_type(8))) short bf16x8;
typedef __attribute__((ext_vector_type(16))) float f32x16;

static __device__ __forceinline__ ushort f2bf(float f) {
    unsigned int u = __float_as_uint(f);
    return (ushort)((u + 0x7FFFu + ((u >> 16) & 1u)) >> 16);  // RNE
}

// ---------- estep body ----------
// logit(x;k) = c + sum_d x_d*(b_d - a_d*x_d), a=0.5/v, b=mu/v,
// c = log pi - 0.5*sum log v - 0.5*sum mu^2/v.
// MODE 0: write per-chunk moment partials. MODE 1: write R[b][n][k].
template <int MODE, int FIRST>
static __device__ __forceinline__ void estep_body(
    int blk, const float* __restrict__ x, const float* __restrict__ mu0,
    const float* __restrict__ partIn, float* __restrict__ partOut,
    float* __restrict__ Rout) {
    const int b = blk >> 4;       // 32 b
    const int chunk = blk & 15;   // 16 chunks of 128 n
    const int tid = threadIdx.x;
    const int wave = tid >> 6;
    const int lane = tid & 63;
    const int k = lane & 31;
    const int jj = lane >> 5;

    float ak[DD], bk[DD], ck;
    if (FIRST) {
        float msq = 0.f;
        const float4* mp = (const float4*)(mu0 + (size_t)(b * KK + k) * DD);
#pragma unroll
        for (int q = 0; q < 4; q++) {
            float4 m4 = mp[q];
            bk[q*4+0]=m4.x; bk[q*4+1]=m4.y; bk[q*4+2]=m4.z; bk[q*4+3]=m4.w;
            msq += m4.x*m4.x + m4.y*m4.y + m4.z*m4.z + m4.w*m4.w;
        }
#pragma unroll
        for (int d = 0; d < DD; d++) ak[d] = 0.5f;
        ck = -3.4657359028f - 0.5f * msq;   // log(1/32) - 0.5*sum mu^2
    } else {
        float N = 0.f, sxv[DD], sxxv[DD];
#pragma unroll
        for (int d = 0; d < DD; d++) { sxv[d] = 0.f; sxxv[d] = 0.f; }
#pragma unroll
        for (int c = 0; c < PART_C; c++) {
            const float* base = partIn + (size_t)(b * PART_C + c) * PART_STRIDE;
            N += base[k];
#pragma unroll
            for (int d = 0; d < DD; d++) {
                sxv[d]  += base[(1 + d) * 32 + k];
                sxxv[d] += base[(17 + d) * 32 + k];
            }
        }
        float invN = 1.0f / N;
        float sumlog = 0.f, cacc = 0.f;
#pragma unroll
        for (int d = 0; d < DD; d++) {
            float m_ = sxv[d] * invN;
            float v = fmaxf(sxxv[d] * invN - m_ * m_, 1e-12f);
            float is = rsqrtf(v);
            float iv = is * is;
            ak[d] = 0.5f * iv;
            bk[d] = m_ * iv;
            cacc = fmaf(m_ * m_, iv, cacc);
            sumlog += __logf(v);
        }
        ck = __logf(N * (1.0f / NN)) - 0.5f * sumlog - 0.5f * cacc;
    }

    float aN = 0.f, aSx[DD], aSxx[DD];
#pragma unroll
    for (int d = 0; d < DD; d++) { aSx[d] = 0.f; aSxx[d] = 0.f; }

#pragma unroll 4
    for (int i = 0; i < 16; i++) {
        const int n = chunk * 128 + i * 8 + wave * 2 + jj;
        const float4* xp = (const float4*)(x + ((size_t)b * NN + n) * DD);
        float xv[DD];
#pragma unroll
        for (int q = 0; q < 4; q++) {
            float4 v = xp[q];
            xv[q*4+0]=v.x; xv[q*4+1]=v.y; xv[q*4+2]=v.z; xv[q*4+3]=v.w;
        }
        float logit = ck;
#pragma unroll
        for (int d = 0; d < DD; d++) {
            float t1 = fmaf(-ak[d], xv[d], bk[d]);
            logit = fmaf(xv[d], t1, logit);
        }
        float m = logit;
#pragma unroll
        for (int off = 1; off < 32; off <<= 1) m = fmaxf(m, __shfl_xor(m, off));
        float e = __expf(logit - m);
        float ssum = e;
#pragma unroll
        for (int off = 1; off < 32; off <<= 1) ssum += __shfl_xor(ssum, off);
        float g = e / ssum;

        if (MODE == 1) {
            Rout[((size_t)b * NN + n) * KK + k] = g;  // coalesced per half-wave
        } else {
            aN += g;
#pragma unroll
            for (int d = 0; d < DD; d++) {
                aSx[d] = fmaf(g, xv[d], aSx[d]);
                aSxx[d] = fmaf(g * xv[d], xv[d], aSxx[d]);
            }
        }
    }

    if (MODE == 0) {
        __shared__ float red[4][KK * 33];
        aN += __shfl_xor(aN, 32);
#pragma unroll
        for (int d = 0; d < DD; d++) {
            aSx[d] += __shfl_xor(aSx[d], 32);
            aSxx[d] += __shfl_xor(aSxx[d], 32);
        }
        if (jj == 0) {
            red[wave][k * 33 + 0] = aN;
#pragma unroll
            for (int d = 0; d < DD; d++) {
                red[wave][k * 33 + 1 + d] = aSx[d];
                red[wave][k * 33 + 17 + d] = aSxx[d];
            }
        }
        __syncthreads();
        float* outp = partOut + (size_t)(b * PART_C + chunk) * PART_STRIDE;
        for (int idx = tid; idx < KK * 33; idx += 256) {
            int kk = idx & 31, j = idx >> 5;
            float v = red[0][kk * 33 + j] + red[1][kk * 33 + j] +
                      red[2][kk * 33 + j] + red[3][kk * 33 + j];
            outp[idx] = v;
        }
    }
}

static __device__ __forceinline__ void xpack_body(int blk, const float* __restrict__ x,
                                                  ushort* __restrict__ xpk) {
    int idx = blk * 256 + threadIdx.x;   // n*64 + l
    int n = idx >> 6, l = idx & 63;
    int b = l & 31, e0 = (l >> 5) * 8;
    const float4* xp = (const float4*)(x + ((size_t)b * NN + n) * DD + e0);
    float4 a = xp[0], c = xp[1];
    ushort* o = xpk + (size_t)idx * 8;
    o[0]=f2bf(a.x); o[1]=f2bf(a.y); o[2]=f2bf(a.z); o[3]=f2bf(a.w);
    o[4]=f2bf(c.x); o[5]=f2bf(c.y); o[6]=f2bf(c.z); o[7]=f2bf(c.w);
}

__global__ __launch_bounds__(256, 4) void k_fused1(
    const float* __restrict__ x, const float* __restrict__ mu0,
    float* __restrict__ partOut, ushort* __restrict__ xpk) {
    if (blockIdx.x < 512)
        estep_body<0, 1>(blockIdx.x, x, mu0, nullptr, partOut, nullptr);
    else
        xpack_body(blockIdx.x - 512, x, xpk);
}

template <int MODE>
__global__ __launch_bounds__(256, 4) void k_estep(
    const float* __restrict__ x, const float* __restrict__ partIn,
    float* __restrict__ partOut, float* __restrict__ Rout) {
    estep_body<MODE, 0>(blockIdx.x, x, nullptr, partIn, partOut, Rout);
}

// v10 MFMA caps: block = (chunk of 8 n) x (k-half). Wave covers 2 t-tiles
// (ii loop) -> block spans 16 k -> each R[b][n][.] line read at most 2x
// grid-wide and block's R working set (32KB) is L1-resident. W streamed once.
__global__ __launch_bounds__(256, 4) void k_caps(
    const float* __restrict__ W, const ushort* __restrict__ xpk,
    const float* __restrict__ R, float* __restrict__ s) {
    const int tid = threadIdx.x;
    const int wv = tid >> 6, l = tid & 63;
    const int chunk = blockIdx.x >> 1, half = blockIdx.x & 1;
    const int col = l & 31, hi = l >> 5;
    const int kq = (l >> 4) & 1;
    float* sc = s + (size_t)chunk * (BN * KK * DD);

    float sacc[2][16];
#pragma unroll
    for (int ii = 0; ii < 2; ii++)
#pragma unroll
        for (int q = 0; q < 16; q++) sacc[ii][q] = 0.f;
    const f32x16 zacc = {0.f,0.f,0.f,0.f, 0.f,0.f,0.f,0.f,
                         0.f,0.f,0.f,0.f, 0.f,0.f,0.f,0.f};

#pragma unroll 2
    for (int i = 0; i < 8; i++) {
        const int n = chunk * 8 + i;
        bf16x8 af = *(const bf16x8*)(xpk + ((size_t)n * 64 + l) * 8);
#pragma unroll
        for (int ii = 0; ii < 2; ii++) {
            const int t = half * 8 + wv * 2 + ii;   // kd-tile 0..15
            const float4* wp = (const float4*)(W + (((size_t)n * 512 + t * 32 + col) * DD) + hi * 8);
            float4 wlo = wp[0], whi = wp[1];
            bf16x8 bfr;
            bfr[0]=(short)f2bf(wlo.x); bfr[1]=(short)f2bf(wlo.y);
            bfr[2]=(short)f2bf(wlo.z); bfr[3]=(short)f2bf(wlo.w);
            bfr[4]=(short)f2bf(whi.x); bfr[5]=(short)f2bf(whi.y);
            bfr[6]=(short)f2bf(whi.z); bfr[7]=(short)f2bf(whi.w);
            const float* rn = R + (size_t)(4 * hi) * (NN * KK) + (size_t)n * KK + 2 * t + kq;
            float r0  = rn[(size_t) 0 * (NN * KK)];
            float r1  = rn[(size_t) 1 * (NN * KK)];
            float r2  = rn[(size_t) 2 * (NN * KK)];
            float r3  = rn[(size_t) 3 * (NN * KK)];
            float r4  = rn[(size_t) 8 * (NN * KK)];
            float r5  = rn[(size_t) 9 * (NN * KK)];
            float r6  = rn[(size_t)10 * (NN * KK)];
            float r7  = rn[(size_t)11 * (NN * KK)];
            float r8  = rn[(size_t)16 * (NN * KK)];
            float r9  = rn[(size_t)17 * (NN * KK)];
            float r10 = rn[(size_t)18 * (NN * KK)];
            float r11 = rn[(size_t)19 * (NN * KK)];
            float r12 = rn[(size_t)24 * (NN * KK)];
            float r13 = rn[(size_t)25 * (NN * KK)];
            float r14 = rn[(size_t)26 * (NN * KK)];
            float r15 = rn[(size_t)27 * (NN * KK)];

            f32x16 D = __builtin_amdgcn_mfma_f32_32x32x16_bf16(af, bfr, zacc, 0, 0, 0);

            sacc[ii][0]  = fmaf(r0,  D[0],  sacc[ii][0]);
            sacc[ii][1]  = fmaf(r1,  D[1],  sacc[ii][1]);
            sacc[ii][2]  = fmaf(r2,  D[2],  sacc[ii][2]);
            sacc[ii][3]  = fmaf(r3,  D[3],  sacc[ii][3]);
            sacc[ii][4]  = fmaf(r4,  D[4],  sacc[ii][4]);
            sacc[ii][5]  = fmaf(r5,  D[5],  sacc[ii][5]);
            sacc[ii][6]  = fmaf(r6,  D[6],  sacc[ii][6]);
            sacc[ii][7]  = fmaf(r7,  D[7],  sacc[ii][7]);
            sacc[ii][8]  = fmaf(r8,  D[8],  sacc[ii][8]);
            sacc[ii][9]  = fmaf(r9,  D[9],  sacc[ii][9]);
            sacc[ii][10] = fmaf(r10, D[10], sacc[ii][10]);
            sacc[ii][11] = fmaf(r11, D[11], sacc[ii][11]);
            sacc[ii][12] = fmaf(r12, D[12], sacc[ii][12]);
            sacc[ii][13] = fmaf(r13, D[13], sacc[ii][13]);
            sacc[ii][14] = fmaf(r14, D[14], sacc[ii][14]);
            sacc[ii][15] = fmaf(r15, D[15], sacc[ii][15]);
        }
    }

#pragma unroll
    for (int ii = 0; ii < 2; ii++) {
        const int t = half * 8 + wv * 2 + ii;
        const int kd = t * 32 + col;
#pragma unroll
        for (int q = 0; q < 16; q++) {
            const int b = (q & 3) + 8 * (q >> 2) + 4 * hi;  // verified C/D row map
            sc[(size_t)b * (KK * DD) + kd] = sacc[ii][q];   // disjoint plain store
        }
    }
}

// thread per (b,k,d); sum SCAPS copies; 16-lane shuffle for the norm.
__global__ void k_squash(const float* __restrict__ s, float* __restrict__ out) {
    int idx = blockIdx.x * 256 + threadIdx.x;  // 16384 = BN*KK*DD
    float v = 0.f;
#pragma unroll 8
    for (int c = 0; c < SCAPS; c++) v += s[(size_t)c * (BN * KK * DD) + idx];
    float ss = v * v;
#pragma unroll
    for (int off = 1; off < 16; off <<= 1) ss += __shfl_xor(ss, off);
    ss += 1e-7f;
    float scale = sqrtf(ss) / (1.0f + ss);
    out[idx] = v * scale;
}

extern "C" void kernel_launch(void* const* d_in, const int* in_sizes, int n_in,
                              void* d_out, int out_size, void* d_ws, size_t ws_size,
                              hipStream_t stream) {
    const float* x   = (const float*)d_in[0];
    const float* W   = (const float*)d_in[1];
    const float* mu0 = (const float*)d_in[2];
    float* ws    = (float*)d_ws;
    float* partA = ws;
    float* partB = ws + 540672;
    float* s     = ws + 1081344;
    float* R     = ws + 5275648;
    ushort* xpk  = (ushort*)(ws + 7372800);

    // 1: EM iter1 partials + x bf16 pack (independent, fused)
    k_fused1<<<1024, 256, 0, stream>>>(x, mu0, partA, xpk);
    // 2: EM iter2 (inline-finalize from partA) -> partB
    k_estep<0><<<512, 256, 0, stream>>>(x, partA, partB, nullptr);
    // 3: EM iter3 (inline-finalize from partB) -> R
    k_estep<1><<<512, 256, 0, stream>>>(x, partB, nullptr, R);
    // 4: caps einsum (MFMA), k-half per block, plain stores
    k_caps<<<512, 256, 0, stream>>>(W, xpk, R, s);
    // 5: reduce copies + squash
    k_squash<<<64, 256, 0, stream>>>(s, (float*)d_out);
}